// Round 5
// baseline (484.160 us; speedup 1.0000x reference)
//
#include <hip/hip_runtime.h>

// Fused double-softmax attention, fp32. B=4 H=8 S=1024 D=64.
// Outputs: context [B,H,S,D] then attn [B,H,S,S], fp32.
// R5: BQ=8 -> ~35KB LDS/block -> 3-4 blocks/CU. No K/V LDS staging (L2-resident).
constexpr int B_ = 4, H_ = 8, S_ = 1024, D_ = 64;
constexpr int BQ = 8;       // q rows per block
constexpr int NT = 512;     // threads per block
constexpr int SP = S_ + 4;  // sc row stride (pad)

__device__ __forceinline__ float wred(float v) {
#pragma unroll
  for (int off = 32; off > 0; off >>= 1) v += __shfl_xor(v, off);
  return v;
}

__global__ __launch_bounds__(NT, 3)
void fused_attn(const float* __restrict__ Q, const float* __restrict__ K,
                const float* __restrict__ V, const int* __restrict__ mask,
                const float* __restrict__ adj, const float* __restrict__ dist,
                const float* __restrict__ cw, const float* __restrict__ cb,
                float* __restrict__ outC, float* __restrict__ outA)
{
  __shared__ float lQ[BQ][D_];     // 2 KB
  __shared__ float sc[BQ][SP];     // 32.9 KB (reused as reduce scratch at end)
  __shared__ float apart[8][4];
  __shared__ float rinv1[BQ];
  __shared__ float rinv2[BQ];

  const int tid = threadIdx.x;
  // bijective XCD-chunked swizzle (4096 blocks = 8 XCDs x 512)
  const int sw = (blockIdx.x & 7) * 512 + (blockIdx.x >> 3);
  const int qt = sw & 127;          // 128 q-tiles per (b,h)
  const int bh = sw >> 7;
  const int q0 = qt * BQ;

  const float* Qp = Q + ((size_t)bh * S_ + q0) * D_;
  const float* Kp = K + (size_t)bh * S_ * D_;
  const float* Vp = V + (size_t)bh * S_ * D_;
  const size_t rb = ((size_t)bh * S_ + q0) * S_;

  if (tid < BQ * D_ / 4) {          // load Q tile (8x64 = 128 float4)
    int q = tid >> 4, d4 = (tid & 15) << 2;
    *reinterpret_cast<float4*>(&lQ[q][d4]) =
        *reinterpret_cast<const float4*>(Qp + q * D_ + d4);
  }
  const float w0 = cw[0], w1 = cw[1], w2 = cw[2], bb = cb[0];
  const int wave = tid >> 6;
  const int lane = tid & 63;
  __syncthreads();

  // ===== Phase A: e = exp(QK^T/8), masked -> -1 sentinel =====================
  // qg = tid>>8 owns q rows 4qg..4qg+3 (lQ reads wave-broadcast); kk = tid&255.
  const int qg = tid >> 8;
  const int kk = tid & 255;
  const int qr = 4 * qg;
  float s[4] = {0.f, 0.f, 0.f, 0.f};

  for (int c = 0; c < 4; ++c) {
    const int kg = c * 256 + kk;
    const float* Kr = Kp + (size_t)kg * D_;
    float acc[4] = {0.f, 0.f, 0.f, 0.f};
#pragma unroll 4
    for (int d4 = 0; d4 < D_; d4 += 4) {
      const float4 kv = *reinterpret_cast<const float4*>(Kr + d4);
#pragma unroll
      for (int i = 0; i < 4; ++i) {
        const float4 qv = *reinterpret_cast<const float4*>(&lQ[qr + i][d4]);
        acc[i] += qv.x * kv.x + qv.y * kv.y + qv.z * kv.z + qv.w * kv.w;
      }
    }
#pragma unroll
    for (int i = 0; i < 4; ++i) {
      const int m = mask[rb + (size_t)(qr + i) * S_ + kg];
      const float e = m ? -1.f : __expf(acc[i] * 0.125f);
      sc[qr + i][kg] = e;
      s[i] += m ? 0.f : e;
    }
  }
#pragma unroll
  for (int i = 0; i < 4; ++i) s[i] = wred(s[i]);
  if (lane == 0) {
#pragma unroll
    for (int i = 0; i < 4; ++i) apart[wave][i] = s[i];
  }
  __syncthreads();
  if (tid < BQ) {                   // row q = 4g+i, sum over waves 4g..4g+3
    const int g = tid >> 2, i = tid & 3;
    rinv1[tid] = 1.f / (apart[4 * g][i] + apart[4 * g + 1][i] +
                        apart[4 * g + 2][i] + apart[4 * g + 3][i]);
  }
  __syncthreads();

  // ===== Phase B: aw = exp(w0*p + w1*dist + w2*adj + b); wave per row ========
  {
    const int q = wave;
    const float i1 = rinv1[q];
    const size_t base = rb + (size_t)q * S_;
    float s2 = 0.f;
#pragma unroll
    for (int swp = 0; swp < 4; ++swp) {
      const int k4 = swp * 256 + lane * 4;
      float4 e = *reinterpret_cast<const float4*>(&sc[q][k4]);
      float4 dv = *reinterpret_cast<const float4*>(dist + base + k4);
      float4 av = *reinterpret_cast<const float4*>(adj + base + k4);
      float4 aw;
      aw.x = (e.x < 0.f) ? 0.f : __expf(w0 * (e.x * i1) + w1 * dv.x + w2 * av.x + bb);
      aw.y = (e.y < 0.f) ? 0.f : __expf(w0 * (e.y * i1) + w1 * dv.y + w2 * av.y + bb);
      aw.z = (e.z < 0.f) ? 0.f : __expf(w0 * (e.z * i1) + w1 * dv.z + w2 * av.z + bb);
      aw.w = (e.w < 0.f) ? 0.f : __expf(w0 * (e.w * i1) + w1 * dv.w + w2 * av.w + bb);
      *reinterpret_cast<float4*>(&sc[q][k4]) = aw;
      s2 += aw.x + aw.y + aw.z + aw.w;
    }
    s2 = wred(s2);
    const float i2 = 1.f / s2;
    if (lane == 0) rinv2[q] = i2;
    // write normalized attn (re-read sc to keep register pressure low)
#pragma unroll
    for (int swp = 0; swp < 4; ++swp) {
      const int k4 = swp * 256 + lane * 4;
      float4 aw = *reinterpret_cast<const float4*>(&sc[q][k4]);
      float4 o = make_float4(aw.x * i2, aw.y * i2, aw.z * i2, aw.w * i2);
      *reinterpret_cast<float4*>(outA + base + k4) = o;
    }
  }
  __syncthreads();

  // ===== Phase C: PV. thread (ke eighth, qp pair, d quad), V from global =====
  const int ke = wave;                // k in [128ke, 128ke+128)
  const int qp = (tid >> 4) & 3;
  const int d4i = tid & 15;
  const int d4c = d4i << 2;
  const int qa = 2 * qp, qb = 2 * qp + 1;
  const int kb = ke * 128;
  const float* Vq = Vp + (size_t)kb * D_ + d4c;
  float4 c0 = make_float4(0.f, 0.f, 0.f, 0.f);
  float4 c1 = make_float4(0.f, 0.f, 0.f, 0.f);

#pragma unroll 2
  for (int j = 0; j < 128; j += 4) {
    const float4 p0 = *reinterpret_cast<const float4*>(&sc[qa][kb + j]);
    const float4 p1 = *reinterpret_cast<const float4*>(&sc[qb][kb + j]);
    const float4 v0 = *reinterpret_cast<const float4*>(Vq + (size_t)(j + 0) * D_);
    const float4 v1 = *reinterpret_cast<const float4*>(Vq + (size_t)(j + 1) * D_);
    const float4 v2 = *reinterpret_cast<const float4*>(Vq + (size_t)(j + 2) * D_);
    const float4 v3 = *reinterpret_cast<const float4*>(Vq + (size_t)(j + 3) * D_);
    c0.x += p0.x * v0.x + p0.y * v1.x + p0.z * v2.x + p0.w * v3.x;
    c0.y += p0.x * v0.y + p0.y * v1.y + p0.z * v2.y + p0.w * v3.y;
    c0.z += p0.x * v0.z + p0.y * v1.z + p0.z * v2.z + p0.w * v3.z;
    c0.w += p0.x * v0.w + p0.y * v1.w + p0.z * v2.w + p0.w * v3.w;
    c1.x += p1.x * v0.x + p1.y * v1.x + p1.z * v2.x + p1.w * v3.x;
    c1.y += p1.x * v0.y + p1.y * v1.y + p1.z * v2.y + p1.w * v3.y;
    c1.z += p1.x * v0.z + p1.y * v1.z + p1.z * v2.z + p1.w * v3.z;
    c1.w += p1.x * v0.w + p1.y * v1.w + p1.z * v2.w + p1.w * v3.w;
  }
  __syncthreads();                      // all PV reads of sc done
  float4* scratch = reinterpret_cast<float4*>(&sc[0][0]);   // 1024 float4 = 16 KB
  scratch[2 * tid] = c0;
  scratch[2 * tid + 1] = c1;
  __syncthreads();
  if (tid < 128) {                      // combine k-eighths + write context
    const int qp2 = tid >> 5, r = (tid >> 4) & 1, di = tid & 15;
    const int q = 2 * qp2 + r;
    float4 s0 = make_float4(0.f, 0.f, 0.f, 0.f);
#pragma unroll
    for (int m = 0; m < 8; ++m) {
      float4 p = scratch[2 * (m * 64 + qp2 * 16 + di) + r];
      s0.x += p.x; s0.y += p.y; s0.z += p.z; s0.w += p.w;
    }
    const float i2 = rinv2[q];
    float4 o = make_float4(s0.x * i2, s0.y * i2, s0.z * i2, s0.w * i2);
    *reinterpret_cast<float4*>(outC + ((size_t)bh * S_ + q0 + q) * D_ + (di << 2)) = o;
  }
}

extern "C" void kernel_launch(void* const* d_in, const int* in_sizes, int n_in,
                              void* d_out, int out_size, void* d_ws, size_t ws_size,
                              hipStream_t stream) {
  const float* Q    = (const float*)d_in[0];
  const float* K    = (const float*)d_in[1];
  const float* V    = (const float*)d_in[2];
  const int*   mask = (const int*)  d_in[3];
  const float* adj  = (const float*)d_in[4];
  const float* dist = (const float*)d_in[5];
  const float* cw   = (const float*)d_in[6];
  const float* cb   = (const float*)d_in[7];

  float* outC = (float*)d_out;                                   // [B,H,S,D]
  float* outA = outC + (size_t)B_ * H_ * S_ * D_;                // [B,H,S,S]

  fused_attn<<<dim3(B_ * H_ * (S_ / BQ)), NT, 0, stream>>>(
      Q, K, V, mask, adj, dist, cw, cb, outC, outA);
}

// Round 6
// 208.450 us; speedup vs baseline: 2.3227x; 2.3227x over previous
//
#include <hip/hip_runtime.h>

// Fused double-softmax attention, fp32 in/out, f16 MFMA for QK^T and PV.
// B=4 H=8 S=1024 D=64. Outputs: context [B,H,S,D] then attn [B,H,S,S].
typedef _Float16 f16;
typedef _Float16 f16x8 __attribute__((ext_vector_type(8)));
typedef _Float16 f16x4 __attribute__((ext_vector_type(4)));
typedef float f32x4 __attribute__((ext_vector_type(4)));

constexpr int B_ = 4, H_ = 8, S_ = 1024, D_ = 64;
constexpr int BQ = 16;        // q rows per block
constexpr int NT = 512;       // 8 waves
constexpr int KC = 128;       // k-chunk
constexpr int KH_LD = 72;     // Kh/Qh row stride in f16 (16B-aligned, bank-min b128)
constexpr int VT_LD = 136;    // Vt row stride in f16 [64 d][136 k]
constexpr int SC_LD = 1032;   // sch row stride in f16

__device__ __forceinline__ float wred(float v) {
#pragma unroll
  for (int off = 32; off > 0; off >>= 1) v += __shfl_xor(v, off);
  return v;
}

__global__ __launch_bounds__(NT)
void fused_attn(const float* __restrict__ Q, const float* __restrict__ K,
                const float* __restrict__ V, const int* __restrict__ mask,
                const float* __restrict__ adj, const float* __restrict__ dist,
                const float* __restrict__ cw, const float* __restrict__ cb,
                float* __restrict__ outC, float* __restrict__ outA)
{
  __shared__ __align__(16) f16 Qh[BQ * KH_LD];        // 2.3 KB
  __shared__ __align__(16) char kv[KC * KH_LD * 2];   // 18.4 KB: Kh | Vt | f32 scratch
  __shared__ __align__(16) f16 sch[BQ * SC_LD];       // 33.0 KB
  __shared__ float rs1w[8][16];
  __shared__ float rinv1[BQ];
  __shared__ float rinv2[BQ];
  f16* Kh = (f16*)kv;
  f16* Vt = (f16*)kv;
  float* fscr = (float*)kv;

  const int tid = threadIdx.x;
  // bijective XCD swizzle: 2048 blocks = 8 XCDs x 256 (4 heads per XCD)
  const int sw = (blockIdx.x & 7) * 256 + (blockIdx.x >> 3);
  const int qt = sw & 63;
  const int bh = sw >> 6;
  const int q0 = qt * BQ;
  const int wv = tid >> 6;    // wave 0..7
  const int ln = tid & 63;
  const int lg = ln >> 4;     // lane group 0..3
  const int li = ln & 15;

  const float* Qp = Q + ((size_t)bh * S_ + q0) * D_;
  const float* Kp = K + (size_t)bh * S_ * D_;
  const float* Vp = V + (size_t)bh * S_ * D_;
  const size_t rb = ((size_t)bh * S_ + q0) * S_;

  // stage Q tile -> f16
  if (tid < 256) {
    const int q = tid >> 4, c4 = (tid & 15) << 2;
    float4 v = *(const float4*)(Qp + q * D_ + c4);
    f16* d = &Qh[q * KH_LD + c4];
    d[0] = (f16)v.x; d[1] = (f16)v.y; d[2] = (f16)v.z; d[3] = (f16)v.w;
  }
  const float w0 = cw[0], w1 = cw[1], w2 = cw[2], bb = cb[0];

  // ===== Phase A: scores via MFMA, e = exp(s/8), masked -> -1 sentinel =======
  float rs[4] = {0.f, 0.f, 0.f, 0.f};
  for (int c = 0; c < 8; ++c) {
    __syncthreads();
#pragma unroll
    for (int i = 0; i < 4; ++i) {            // stage K chunk (coalesced) -> f16
      const int f = tid + NT * i;
      const int r = f >> 4, c4 = (f & 15) << 2;
      float4 v = *(const float4*)(Kp + (size_t)(c * KC + r) * D_ + c4);
      f16* d = &Kh[r * KH_LD + c4];
      d[0] = (f16)v.x; d[1] = (f16)v.y; d[2] = (f16)v.z; d[3] = (f16)v.w;
    }
    __syncthreads();
    // wave wv: 16(q) x 16(k) tile at k-cols n0..n0+15
    const int n0 = wv * 16;
    f32x4 acc = {0.f, 0.f, 0.f, 0.f};
#pragma unroll
    for (int s = 0; s < 2; ++s) {
      f16x8 a = *(const f16x8*)&Qh[li * KH_LD + s * 32 + lg * 8];
      f16x8 b = *(const f16x8*)&Kh[(n0 + li) * KH_LD + s * 32 + lg * 8];
      acc = __builtin_amdgcn_mfma_f32_16x16x32_f16(a, b, acc, 0, 0, 0);
    }
    const int kg = c * KC + n0 + li;
#pragma unroll
    for (int r = 0; r < 4; ++r) {            // D[m][n]: m=lg*4+r, n=li
      const int m = lg * 4 + r;
      const int msk = mask[rb + (size_t)m * S_ + kg];
      const float e = msk ? -1.f : __expf(acc[r] * 0.125f);
      sch[m * SC_LD + kg] = (f16)e;
      rs[r] += msk ? 0.f : e;
    }
  }
#pragma unroll
  for (int r = 0; r < 4; ++r) {              // reduce over the 16 lanes per group
    rs[r] += __shfl_xor(rs[r], 1); rs[r] += __shfl_xor(rs[r], 2);
    rs[r] += __shfl_xor(rs[r], 4); rs[r] += __shfl_xor(rs[r], 8);
  }
  if (li == 0) {
#pragma unroll
    for (int r = 0; r < 4; ++r) rs1w[wv][lg * 4 + r] = rs[r];
  }
  __syncthreads();
  if (tid < BQ) {
    float t = 0.f;
#pragma unroll
    for (int w = 0; w < 8; ++w) t += rs1w[w][tid];
    rinv1[tid] = 1.f / t;
  }
  __syncthreads();

  // ===== Phase B: aw = exp(w0*p + w1*dist + w2*adj + b); wave -> rows 2wv,2wv+1
#pragma unroll
  for (int rr = 0; rr < 2; ++rr) {
    const int q = 2 * wv + rr;
    const float i1 = rinv1[q];
    const size_t base = rb + (size_t)q * S_;
    float s2 = 0.f;
#pragma unroll
    for (int swp = 0; swp < 4; ++swp) {
      const int k4 = swp * 256 + ln * 4;
      f16x4 ef = *(const f16x4*)&sch[q * SC_LD + k4];
      float4 dv = *(const float4*)(dist + base + k4);
      float4 av = *(const float4*)(adj + base + k4);
      const float e0 = (float)ef[0], e1 = (float)ef[1];
      const float e2 = (float)ef[2], e3 = (float)ef[3];
      const float a0 = (e0 < 0.f) ? 0.f : __expf(w0 * (e0 * i1) + w1 * dv.x + w2 * av.x + bb);
      const float a1 = (e1 < 0.f) ? 0.f : __expf(w0 * (e1 * i1) + w1 * dv.y + w2 * av.y + bb);
      const float a2 = (e2 < 0.f) ? 0.f : __expf(w0 * (e2 * i1) + w1 * dv.z + w2 * av.z + bb);
      const float a3 = (e3 < 0.f) ? 0.f : __expf(w0 * (e3 * i1) + w1 * dv.w + w2 * av.w + bb);
      f16x4 af; af[0] = (f16)a0; af[1] = (f16)a1; af[2] = (f16)a2; af[3] = (f16)a3;
      *(f16x4*)&sch[q * SC_LD + k4] = af;
      s2 += a0 + a1 + a2 + a3;
    }
    s2 = wred(s2);
    const float i2 = 1.f / s2;
    if (ln == 0) rinv2[q] = i2;
#pragma unroll
    for (int swp = 0; swp < 4; ++swp) {      // normalized attn out (f16-rounded aw)
      const int k4 = swp * 256 + ln * 4;
      f16x4 af = *(const f16x4*)&sch[q * SC_LD + k4];
      float4 o = make_float4((float)af[0] * i2, (float)af[1] * i2,
                             (float)af[2] * i2, (float)af[3] * i2);
      *(float4*)(outA + base + k4) = o;
    }
  }

  // ===== Phase C: ctx = P(f16) x V(f16) via MFMA, V staged transposed ========
  const int ntile = wv >> 1;          // d-col tile 0..3 (cols 16*ntile..+15)
  const int spair = (wv & 1) * 2;     // k-step pair within chunk
  f32x4 cacc = {0.f, 0.f, 0.f, 0.f};
  for (int c = 0; c < 8; ++c) {
    __syncthreads();                  // Vt overwrites Kh region / prev chunk
#pragma unroll
    for (int i = 0; i < 4; ++i) {     // stage V chunk transposed -> Vt[d][k]
      const int f = tid + NT * i;
      const int r = f >> 4, c4 = (f & 15) << 2;
      float4 v = *(const float4*)(Vp + (size_t)(c * KC + r) * D_ + c4);
      Vt[(c4 + 0) * VT_LD + r] = (f16)v.x;
      Vt[(c4 + 1) * VT_LD + r] = (f16)v.y;
      Vt[(c4 + 2) * VT_LD + r] = (f16)v.z;
      Vt[(c4 + 3) * VT_LD + r] = (f16)v.w;
    }
    __syncthreads();
#pragma unroll
    for (int u = 0; u < 2; ++u) {
      const int s = spair + u;
      f16x8 a = *(const f16x8*)&sch[li * SC_LD + c * KC + s * 32 + lg * 8];
      f16x8 b = *(const f16x8*)&Vt[(ntile * 16 + li) * VT_LD + s * 32 + lg * 8];
      cacc = __builtin_amdgcn_mfma_f32_16x16x32_f16(a, b, cacc, 0, 0, 0);
    }
  }
  __syncthreads();
  *(f32x4*)&fscr[(wv * 64 + ln) * 4] = cacc;   // reuse kv buffer as f32 scratch
  __syncthreads();
  if (tid < 256) {                    // combine wave pairs, scale, write ctx
    const int t = tid >> 6, l2 = tid & 63;
    const int g2 = l2 >> 4, n = l2 & 15;
    f32x4 p  = *(const f32x4*)&fscr[((2 * t) * 64 + l2) * 4];
    f32x4 p2 = *(const f32x4*)&fscr[((2 * t + 1) * 64 + l2) * 4];
#pragma unroll
    for (int r = 0; r < 4; ++r) {
      const int m = g2 * 4 + r;
      outC[((size_t)bh * S_ + q0 + m) * D_ + t * 16 + n] = (p[r] + p2[r]) * rinv2[m];
    }
  }
}

extern "C" void kernel_launch(void* const* d_in, const int* in_sizes, int n_in,
                              void* d_out, int out_size, void* d_ws, size_t ws_size,
                              hipStream_t stream) {
  const float* Q    = (const float*)d_in[0];
  const float* K    = (const float*)d_in[1];
  const float* V    = (const float*)d_in[2];
  const int*   mask = (const int*)  d_in[3];
  const float* adj  = (const float*)d_in[4];
  const float* dist = (const float*)d_in[5];
  const float* cw   = (const float*)d_in[6];
  const float* cb   = (const float*)d_in[7];

  float* outC = (float*)d_out;                                   // [B,H,S,D]
  float* outA = outC + (size_t)B_ * H_ * S_ * D_;                // [B,H,S,S]

  fused_attn<<<dim3(B_ * H_ * (S_ / BQ)), NT, 0, stream>>>(
      Q, K, V, mask, adj, dist, cw, cb, outC, outA);
}

// Round 7
// 176.038 us; speedup vs baseline: 2.7503x; 1.1841x over previous
//
#include <hip/hip_runtime.h>

// Fused double-softmax attention, fp32 in/out, f16 MFMA for QK^T and PV.
// B=4 H=8 S=1024 D=64. Outputs: context [B,H,S,D] then attn [B,H,S,S].
// R7: register-transpose V staging (conflict-free b128 LDS writes),
//     hoisted Q fragments, early mask loads.
typedef _Float16 f16;
typedef _Float16 f16x8 __attribute__((ext_vector_type(8)));
typedef _Float16 f16x4 __attribute__((ext_vector_type(4)));
typedef float f32x4 __attribute__((ext_vector_type(4)));

constexpr int B_ = 4, H_ = 8, S_ = 1024, D_ = 64;
constexpr int BQ = 16;        // q rows per block
constexpr int NT = 512;       // 8 waves
constexpr int KC = 128;       // k-chunk
constexpr int KH_LD = 72;     // Kh/Qh row stride in f16 (16B-aligned)
constexpr int VT_LD = 136;    // Vt row stride in f16 [64 d][136 k]
constexpr int SC_LD = 1032;   // sch row stride in f16

__device__ __forceinline__ float wred(float v) {
#pragma unroll
  for (int off = 32; off > 0; off >>= 1) v += __shfl_xor(v, off);
  return v;
}

__global__ __launch_bounds__(NT)
void fused_attn(const float* __restrict__ Q, const float* __restrict__ K,
                const float* __restrict__ V, const int* __restrict__ mask,
                const float* __restrict__ adj, const float* __restrict__ dist,
                const float* __restrict__ cw, const float* __restrict__ cb,
                float* __restrict__ outC, float* __restrict__ outA)
{
  __shared__ __align__(16) f16 Qh[BQ * KH_LD];        // 2.3 KB
  __shared__ __align__(16) char kv[KC * KH_LD * 2];   // 18.4 KB: Kh | Vt | f32 scratch
  __shared__ __align__(16) f16 sch[BQ * SC_LD];       // 33.0 KB
  __shared__ float rs1w[8][16];
  __shared__ float rinv1[BQ];
  __shared__ float rinv2[BQ];
  f16* Kh = (f16*)kv;
  f16* Vt = (f16*)kv;
  float* fscr = (float*)kv;

  const int tid = threadIdx.x;
  // bijective XCD swizzle: 2048 blocks = 8 XCDs x 256 (4 heads per XCD)
  const int sw = (blockIdx.x & 7) * 256 + (blockIdx.x >> 3);
  const int qt = sw & 63;
  const int bh = sw >> 6;
  const int q0 = qt * BQ;
  const int wv = tid >> 6;    // wave 0..7
  const int ln = tid & 63;
  const int lg = ln >> 4;     // lane group 0..3
  const int li = ln & 15;

  const float* Qp = Q + ((size_t)bh * S_ + q0) * D_;
  const float* Kp = K + (size_t)bh * S_ * D_;
  const float* Vp = V + (size_t)bh * S_ * D_;
  const size_t rb = ((size_t)bh * S_ + q0) * S_;

  // stage Q tile -> f16
  if (tid < 256) {
    const int q = tid >> 4, c4 = (tid & 15) << 2;
    float4 v = *(const float4*)(Qp + q * D_ + c4);
    f16* d = &Qh[q * KH_LD + c4];
    d[0] = (f16)v.x; d[1] = (f16)v.y; d[2] = (f16)v.z; d[3] = (f16)v.w;
  }
  const float w0 = cw[0], w1 = cw[1], w2 = cw[2], bb = cb[0];
  __syncthreads();

  // hoist Q fragments (constant across chunks)
  f16x8 aq0 = *(const f16x8*)&Qh[li * KH_LD + 0 * 32 + lg * 8];
  f16x8 aq1 = *(const f16x8*)&Qh[li * KH_LD + 1 * 32 + lg * 8];

  // ===== Phase A: scores via MFMA, e = exp(s/8), masked -> -1 sentinel =======
  const int n0 = wv * 16;
  float rs[4] = {0.f, 0.f, 0.f, 0.f};
  for (int c = 0; c < 8; ++c) {
    __syncthreads();
    // early mask loads for this chunk (drain at next barrier)
    const int kg = c * KC + n0 + li;
    int msk[4];
#pragma unroll
    for (int r = 0; r < 4; ++r)
      msk[r] = mask[rb + (size_t)(lg * 4 + r) * S_ + kg];
#pragma unroll
    for (int i = 0; i < 4; ++i) {            // stage K chunk (coalesced) -> f16
      const int f = tid + NT * i;
      const int r = f >> 4, c4 = (f & 15) << 2;
      float4 v = *(const float4*)(Kp + (size_t)(c * KC + r) * D_ + c4);
      f16* d = &Kh[r * KH_LD + c4];
      d[0] = (f16)v.x; d[1] = (f16)v.y; d[2] = (f16)v.z; d[3] = (f16)v.w;
    }
    __syncthreads();
    f32x4 acc = {0.f, 0.f, 0.f, 0.f};
    {
      f16x8 b0 = *(const f16x8*)&Kh[(n0 + li) * KH_LD + 0 * 32 + lg * 8];
      acc = __builtin_amdgcn_mfma_f32_16x16x32_f16(aq0, b0, acc, 0, 0, 0);
      f16x8 b1 = *(const f16x8*)&Kh[(n0 + li) * KH_LD + 1 * 32 + lg * 8];
      acc = __builtin_amdgcn_mfma_f32_16x16x32_f16(aq1, b1, acc, 0, 0, 0);
    }
#pragma unroll
    for (int r = 0; r < 4; ++r) {            // D[m][n]: m=lg*4+r, n=li
      const int m = lg * 4 + r;
      const float e = msk[r] ? -1.f : __expf(acc[r] * 0.125f);
      sch[m * SC_LD + kg] = (f16)e;
      rs[r] += msk[r] ? 0.f : e;
    }
  }
#pragma unroll
  for (int r = 0; r < 4; ++r) {              // reduce over the 16 lanes per group
    rs[r] += __shfl_xor(rs[r], 1); rs[r] += __shfl_xor(rs[r], 2);
    rs[r] += __shfl_xor(rs[r], 4); rs[r] += __shfl_xor(rs[r], 8);
  }
  if (li == 0) {
#pragma unroll
    for (int r = 0; r < 4; ++r) rs1w[wv][lg * 4 + r] = rs[r];
  }
  __syncthreads();
  if (tid < BQ) {
    float t = 0.f;
#pragma unroll
    for (int w = 0; w < 8; ++w) t += rs1w[w][tid];
    rinv1[tid] = 1.f / t;
  }
  __syncthreads();

  // ===== Phase B: aw = exp(w0*p + w1*dist + w2*adj + b); wave -> rows 2wv,2wv+1
#pragma unroll
  for (int rr = 0; rr < 2; ++rr) {
    const int q = 2 * wv + rr;
    const float i1 = rinv1[q];
    const size_t base = rb + (size_t)q * S_;
    float s2 = 0.f;
#pragma unroll
    for (int swp = 0; swp < 4; ++swp) {
      const int k4 = swp * 256 + ln * 4;
      f16x4 ef = *(const f16x4*)&sch[q * SC_LD + k4];
      float4 dv = *(const float4*)(dist + base + k4);
      float4 av = *(const float4*)(adj + base + k4);
      const float e0 = (float)ef[0], e1 = (float)ef[1];
      const float e2 = (float)ef[2], e3 = (float)ef[3];
      const float a0 = (e0 < 0.f) ? 0.f : __expf(w0 * (e0 * i1) + w1 * dv.x + w2 * av.x + bb);
      const float a1 = (e1 < 0.f) ? 0.f : __expf(w0 * (e1 * i1) + w1 * dv.y + w2 * av.y + bb);
      const float a2 = (e2 < 0.f) ? 0.f : __expf(w0 * (e2 * i1) + w1 * dv.z + w2 * av.z + bb);
      const float a3 = (e3 < 0.f) ? 0.f : __expf(w0 * (e3 * i1) + w1 * dv.w + w2 * av.w + bb);
      f16x4 af; af[0] = (f16)a0; af[1] = (f16)a1; af[2] = (f16)a2; af[3] = (f16)a3;
      *(f16x4*)&sch[q * SC_LD + k4] = af;
      s2 += a0 + a1 + a2 + a3;
    }
    s2 = wred(s2);
    const float i2 = 1.f / s2;
    if (ln == 0) rinv2[q] = i2;
#pragma unroll
    for (int swp = 0; swp < 4; ++swp) {      // normalized attn out (f16-rounded aw)
      const int k4 = swp * 256 + ln * 4;
      f16x4 af = *(const f16x4*)&sch[q * SC_LD + k4];
      float4 o = make_float4((float)af[0] * i2, (float)af[1] * i2,
                             (float)af[2] * i2, (float)af[3] * i2);
      *(float4*)(outA + base + k4) = o;
    }
  }

  // ===== Phase C: ctx = P(f16) x V(f16) via MFMA =============================
  // V staged transposed via REGISTER transpose: lane ln owns column d=ln,
  // reads 8 k via coalesced row reads, writes contiguous f16x8 (conflict-free).
  const int ntile = wv >> 1;          // d-col tile 0..3 (cols 16*ntile..+15)
  const int spair = (wv & 1) * 2;     // k-step pair within chunk
  f32x4 cacc = {0.f, 0.f, 0.f, 0.f};
  for (int c = 0; c < 8; ++c) {
    __syncthreads();                  // prev-chunk PV reads done; Vt reuses Kh space
#pragma unroll
    for (int it = 0; it < 2; ++it) {
      const int oct = wv + 8 * it;    // k-octet 0..15 within chunk
      const float* vsrc = Vp + (size_t)(c * KC + oct * 8) * D_ + ln;
      f16x8 t;
#pragma unroll
      for (int j = 0; j < 8; ++j) t[j] = (f16)vsrc[(size_t)j * D_];
      *(f16x8*)&Vt[ln * VT_LD + oct * 8] = t;
    }
    __syncthreads();
#pragma unroll
    for (int u = 0; u < 2; ++u) {
      const int s = spair + u;
      f16x8 a = *(const f16x8*)&sch[li * SC_LD + c * KC + s * 32 + lg * 8];
      f16x8 b = *(const f16x8*)&Vt[(ntile * 16 + li) * VT_LD + s * 32 + lg * 8];
      cacc = __builtin_amdgcn_mfma_f32_16x16x32_f16(a, b, cacc, 0, 0, 0);
    }
  }
  __syncthreads();
  *(f32x4*)&fscr[(wv * 64 + ln) * 4] = cacc;   // reuse kv buffer as f32 scratch
  __syncthreads();
  if (tid < 256) {                    // combine wave pairs, scale, write ctx
    const int t = tid >> 6, l2 = tid & 63;
    const int g2 = l2 >> 4, n = l2 & 15;
    f32x4 p  = *(const f32x4*)&fscr[((2 * t) * 64 + l2) * 4];
    f32x4 p2 = *(const f32x4*)&fscr[((2 * t + 1) * 64 + l2) * 4];
#pragma unroll
    for (int r = 0; r < 4; ++r) {
      const int m = g2 * 4 + r;
      outC[((size_t)bh * S_ + q0 + m) * D_ + t * 16 + n] = (p[r] + p2[r]) * rinv2[m];
    }
  }
}

extern "C" void kernel_launch(void* const* d_in, const int* in_sizes, int n_in,
                              void* d_out, int out_size, void* d_ws, size_t ws_size,
                              hipStream_t stream) {
  const float* Q    = (const float*)d_in[0];
  const float* K    = (const float*)d_in[1];
  const float* V    = (const float*)d_in[2];
  const int*   mask = (const int*)  d_in[3];
  const float* adj  = (const float*)d_in[4];
  const float* dist = (const float*)d_in[5];
  const float* cw   = (const float*)d_in[6];
  const float* cb   = (const float*)d_in[7];

  float* outC = (float*)d_out;                                   // [B,H,S,D]
  float* outA = outC + (size_t)B_ * H_ * S_ * D_;                // [B,H,S,S]

  fused_attn<<<dim3(B_ * H_ * (S_ / BQ)), NT, 0, stream>>>(
      Q, K, V, mask, adj, dist, cw, cb, outC, outA);
}

// Round 8
// 174.313 us; speedup vs baseline: 2.7775x; 1.0099x over previous
//
#include <hip/hip_runtime.h>

// Fused double-softmax attention, fp32 in/out, f16 MFMA for QK^T and PV.
// B=4 H=8 S=1024 D=64. Outputs: context [B,H,S,D] then attn [B,H,S,S].
// R8: NO K/V LDS staging -- MFMA fragments loaded straight global->reg
// (K/V are L2-resident; each element consumed by exactly one wave).
// Barriers: 34 -> 5. LDS 54.8 -> 44.2 KB -> 3 blocks/CU.
typedef _Float16 f16;
typedef _Float16 f16x8 __attribute__((ext_vector_type(8)));
typedef _Float16 f16x4 __attribute__((ext_vector_type(4)));
typedef float f32x4 __attribute__((ext_vector_type(4)));

constexpr int B_ = 4, H_ = 8, S_ = 1024, D_ = 64;
constexpr int BQ = 16;        // q rows per block
constexpr int NT = 512;       // 8 waves
constexpr int KC = 128;       // k per chunk (one 16-col tile per wave)
constexpr int QH_LD = 72;     // Qh row stride in f16
constexpr int SC_LD = 1032;   // sch row stride in f16

__device__ __forceinline__ float wred(float v) {
#pragma unroll
  for (int off = 32; off > 0; off >>= 1) v += __shfl_xor(v, off);
  return v;
}

__global__ __launch_bounds__(NT)
void fused_attn(const float* __restrict__ Q, const float* __restrict__ K,
                const float* __restrict__ V, const int* __restrict__ mask,
                const float* __restrict__ adj, const float* __restrict__ dist,
                const float* __restrict__ cw, const float* __restrict__ cb,
                float* __restrict__ outC, float* __restrict__ outA)
{
  __shared__ __align__(16) f16 Qh[BQ * QH_LD];     // 2.3 KB
  __shared__ __align__(16) f16 sch[BQ * SC_LD];    // 33.0 KB
  __shared__ __align__(16) float fscr[NT * 4];     // 8 KB
  __shared__ float rs1w[8][16];
  __shared__ float rinv1[BQ];
  __shared__ float rinv2[BQ];

  const int tid = threadIdx.x;
  // bijective XCD swizzle: 2048 blocks = 8 XCDs x 256 (4 heads per XCD)
  const int sw = (blockIdx.x & 7) * 256 + (blockIdx.x >> 3);
  const int qt = sw & 63;
  const int bh = sw >> 6;
  const int q0 = qt * BQ;
  const int wv = tid >> 6;    // wave 0..7
  const int ln = tid & 63;
  const int lg = ln >> 4;     // lane group 0..3
  const int li = ln & 15;

  const float* Qp = Q + ((size_t)bh * S_ + q0) * D_;
  const float* Kp = K + (size_t)bh * S_ * D_;
  const float* Vp = V + (size_t)bh * S_ * D_;
  const size_t rb = ((size_t)bh * S_ + q0) * S_;

  // stage Q tile -> f16
  if (tid < 256) {
    const int q = tid >> 4, c4 = (tid & 15) << 2;
    float4 v = *(const float4*)(Qp + q * D_ + c4);
    f16* d = &Qh[q * QH_LD + c4];
    d[0] = (f16)v.x; d[1] = (f16)v.y; d[2] = (f16)v.z; d[3] = (f16)v.w;
  }
  const float w0 = cw[0], w1 = cw[1], w2 = cw[2], bb = cb[0];
  __syncthreads();                                  // (1)

  // hoist Q fragments (A operand; lane li = q-row li, k = s*32 + lg*8)
  f16x8 aq0 = *(const f16x8*)&Qh[li * QH_LD + 0 * 32 + lg * 8];
  f16x8 aq1 = *(const f16x8*)&Qh[li * QH_LD + 1 * 32 + lg * 8];

  // ===== Phase A: scores via MFMA; K fragments straight from global =========
  // wave wv owns k-cols n0 + c*KC; B-frag lane (lg,li): K row (n0+li),
  // d = s*32 + lg*8 .. +7  (two float4 loads, L2-resident).
  const int n0 = wv * 16;
  float rs[4] = {0.f, 0.f, 0.f, 0.f};
  for (int c = 0; c < 8; ++c) {
    const int kg = c * KC + n0 + li;
    int msk[4];
#pragma unroll
    for (int r = 0; r < 4; ++r)
      msk[r] = mask[rb + (size_t)(lg * 4 + r) * S_ + kg];
    const float* Kr = Kp + (size_t)kg * D_ + lg * 8;
    const float4 ka = *(const float4*)(Kr + 0);
    const float4 kb = *(const float4*)(Kr + 4);
    const float4 kc2 = *(const float4*)(Kr + 32);
    const float4 kd = *(const float4*)(Kr + 36);
    f16x8 b0, b1;
    b0[0] = (f16)ka.x; b0[1] = (f16)ka.y; b0[2] = (f16)ka.z; b0[3] = (f16)ka.w;
    b0[4] = (f16)kb.x; b0[5] = (f16)kb.y; b0[6] = (f16)kb.z; b0[7] = (f16)kb.w;
    b1[0] = (f16)kc2.x; b1[1] = (f16)kc2.y; b1[2] = (f16)kc2.z; b1[3] = (f16)kc2.w;
    b1[4] = (f16)kd.x; b1[5] = (f16)kd.y; b1[6] = (f16)kd.z; b1[7] = (f16)kd.w;
    f32x4 acc = {0.f, 0.f, 0.f, 0.f};
    acc = __builtin_amdgcn_mfma_f32_16x16x32_f16(aq0, b0, acc, 0, 0, 0);
    acc = __builtin_amdgcn_mfma_f32_16x16x32_f16(aq1, b1, acc, 0, 0, 0);
#pragma unroll
    for (int r = 0; r < 4; ++r) {            // D[m][n]: m=lg*4+r, n=li
      const int m = lg * 4 + r;
      const float e = msk[r] ? -1.f : __expf(acc[r] * 0.125f);
      sch[m * SC_LD + kg] = (f16)e;
      rs[r] += msk[r] ? 0.f : e;
    }
  }
#pragma unroll
  for (int r = 0; r < 4; ++r) {              // reduce over 16 lanes per group
    rs[r] += __shfl_xor(rs[r], 1); rs[r] += __shfl_xor(rs[r], 2);
    rs[r] += __shfl_xor(rs[r], 4); rs[r] += __shfl_xor(rs[r], 8);
  }
  if (li == 0) {
#pragma unroll
    for (int r = 0; r < 4; ++r) rs1w[wv][lg * 4 + r] = rs[r];
  }
  __syncthreads();                                  // (2) sch + rs1w visible
  if (tid < BQ) {
    float t = 0.f;
#pragma unroll
    for (int w = 0; w < 8; ++w) t += rs1w[w][tid];
    rinv1[tid] = 1.f / t;
  }
  __syncthreads();                                  // (3)

  // ===== Phase B: aw = exp(w0*p + w1*dist + w2*adj + b); wave -> rows 2wv,2wv+1
#pragma unroll
  for (int rr = 0; rr < 2; ++rr) {
    const int q = 2 * wv + rr;
    const float i1 = rinv1[q];
    const size_t base = rb + (size_t)q * S_;
    float s2 = 0.f;
#pragma unroll
    for (int swp = 0; swp < 4; ++swp) {
      const int k4 = swp * 256 + ln * 4;
      f16x4 ef = *(const f16x4*)&sch[q * SC_LD + k4];
      float4 dv = *(const float4*)(dist + base + k4);
      float4 av = *(const float4*)(adj + base + k4);
      const float e0 = (float)ef[0], e1 = (float)ef[1];
      const float e2 = (float)ef[2], e3 = (float)ef[3];
      const float a0 = (e0 < 0.f) ? 0.f : __expf(w0 * (e0 * i1) + w1 * dv.x + w2 * av.x + bb);
      const float a1 = (e1 < 0.f) ? 0.f : __expf(w0 * (e1 * i1) + w1 * dv.y + w2 * av.y + bb);
      const float a2 = (e2 < 0.f) ? 0.f : __expf(w0 * (e2 * i1) + w1 * dv.z + w2 * av.z + bb);
      const float a3 = (e3 < 0.f) ? 0.f : __expf(w0 * (e3 * i1) + w1 * dv.w + w2 * av.w + bb);
      f16x4 af; af[0] = (f16)a0; af[1] = (f16)a1; af[2] = (f16)a2; af[3] = (f16)a3;
      *(f16x4*)&sch[q * SC_LD + k4] = af;
      s2 += a0 + a1 + a2 + a3;
    }
    s2 = wred(s2);
    const float i2 = 1.f / s2;
    if (ln == 0) rinv2[q] = i2;
#pragma unroll
    for (int swp = 0; swp < 4; ++swp) {      // normalized attn out
      const int k4 = swp * 256 + ln * 4;
      f16x4 af = *(const f16x4*)&sch[q * SC_LD + k4];
      float4 o = make_float4((float)af[0] * i2, (float)af[1] * i2,
                             (float)af[2] * i2, (float)af[3] * i2);
      *(float4*)(outA + base + k4) = o;
    }
  }
  __syncthreads();                                  // (4) sch aw-values visible

  // ===== Phase C: ctx = P(f16) x V(f16); V^T fragments straight from global ==
  // wave wv: d-cols 16*ntile..+15, k-steps spair..spair+1 per chunk.
  // B-frag lane (lg,li): V[k = c*KC + s*32 + lg*8 + j][d0 + li], j=0..7
  // (8 loads, lanes same-lg contiguous 64B, L2-resident).
  const int ntile = wv >> 1;
  const int spair = (wv & 1) * 2;
  const int d0 = ntile * 16 + li;
  f32x4 cacc = {0.f, 0.f, 0.f, 0.f};
  for (int c = 0; c < 8; ++c) {
#pragma unroll
    for (int u = 0; u < 2; ++u) {
      const int s = spair + u;
      const float* Vc = Vp + (size_t)(c * KC + s * 32 + lg * 8) * D_ + d0;
      f16x8 bfr;
#pragma unroll
      for (int j = 0; j < 8; ++j) bfr[j] = (f16)Vc[(size_t)j * D_];
      f16x8 a = *(const f16x8*)&sch[li * SC_LD + c * KC + s * 32 + lg * 8];
      cacc = __builtin_amdgcn_mfma_f32_16x16x32_f16(a, bfr, cacc, 0, 0, 0);
    }
  }
  *(f32x4*)&fscr[tid * 4] = cacc;
  __syncthreads();                                  // (5)
  if (tid < 256) {                    // combine wave pairs, scale, write ctx
    const int t = tid >> 6, l2 = tid & 63;
    const int g2 = l2 >> 4, n = l2 & 15;
    f32x4 p  = *(const f32x4*)&fscr[((2 * t) * 64 + l2) * 4];
    f32x4 p2 = *(const f32x4*)&fscr[((2 * t + 1) * 64 + l2) * 4];
#pragma unroll
    for (int r = 0; r < 4; ++r) {
      const int m = g2 * 4 + r;
      outC[((size_t)bh * S_ + q0 + m) * D_ + t * 16 + n] = (p[r] + p2[r]) * rinv2[m];
    }
  }
}

extern "C" void kernel_launch(void* const* d_in, const int* in_sizes, int n_in,
                              void* d_out, int out_size, void* d_ws, size_t ws_size,
                              hipStream_t stream) {
  const float* Q    = (const float*)d_in[0];
  const float* K    = (const float*)d_in[1];
  const float* V    = (const float*)d_in[2];
  const int*   mask = (const int*)  d_in[3];
  const float* adj  = (const float*)d_in[4];
  const float* dist = (const float*)d_in[5];
  const float* cw   = (const float*)d_in[6];
  const float* cb   = (const float*)d_in[7];

  float* outC = (float*)d_out;                                   // [B,H,S,D]
  float* outA = outC + (size_t)B_ * H_ * S_ * D_;                // [B,H,S,S]

  fused_attn<<<dim3(B_ * H_ * (S_ / BQ)), NT, 0, stream>>>(
      Q, K, V, mask, adj, dist, cw, cb, outC, outA);
}